// Round 11
// baseline (203.865 us; speedup 1.0000x reference)
//
#include <hip/hip_runtime.h>
#include <hip/hip_bf16.h>

// ---------- types ----------
typedef __attribute__((ext_vector_type(8))) short bf16x8;   // 4 VGPR MFMA A/B frag
typedef __attribute__((ext_vector_type(4))) float f32x4;    // 4 VGPR MFMA C/D frag

__device__ __forceinline__ unsigned short f2bf(float f) {
    __hip_bfloat16 h = __float2bfloat16(f);   // RNE
    return __builtin_bit_cast(unsigned short, h);
}

// Problem constants: B=16, C=768, H=W=48 -> HW=2304, tokens/mod = 36864
#define BT 128            // tokens per block (8 waves x 16 tokens)
#define TPM 288           // tiles per modality = 36864/128
#define NCHUNK 24         // 768 / 32

// ---------- single merged prep kernel ----------
// Blocks 0..71: pack g*W1 -> bf16 MFMA B-fragment order
//   w1f[m][kk(24)][nf(12)][lane(64)][8]; lane l holds B[k=(l>>4)*8+j][n=l&15].
// Blocks 72..74: u[d] = sum_c g[c]*W1[c][d], vb[d] = sum_c b[c]*W1[c][d] + B1[d]
__global__ void prep_all(const float* __restrict__ w1, const float* __restrict__ lng,
                         const float* __restrict__ lnb, const float* __restrict__ b1,
                         unsigned short* __restrict__ w1f,
                         float* __restrict__ u, float* __restrict__ vb)
{
    const int b   = blockIdx.x;
    const int tid = threadIdx.x;          // 256 threads
    if (b < 72) {
        const int m  = b / 24;
        const int kk = b % 24;
        __shared__ float ws[32 * 192];
        const float* w1m = w1 + ((size_t)m * 768 + kk * 32) * 192;
        const float* gm  = lng + m * 768 + kk * 32;
        for (int i = tid; i < 6144; i += 256) {
            int cl = i / 192, d = i % 192;
            ws[i] = gm[cl] * w1m[(size_t)cl * 192 + d];
        }
        __syncthreads();
        unsigned short* outp = w1f + ((size_t)m * 24 + kk) * 6144;
        for (int i = tid; i < 6144; i += 256) {
            int nf   = i >> 9;
            int rem  = i & 511;
            int lane = rem >> 3;
            int j    = rem & 7;
            int cl   = ((lane >> 4) << 3) + j;
            int d    = (nf << 4) + (lane & 15);
            outp[i]  = f2bf(ws[cl * 192 + d]);
        }
    } else {
        const int m = b - 72;
        if (tid < 192) {
            const int d = tid;
            const float* w1m = w1 + (size_t)m * 768 * 192;
            const float* gm  = lng + m * 768;
            const float* bm  = lnb + m * 768;
            float su = 0.f, sv = 0.f;
            #pragma unroll 16
            for (int c = 0; c < 768; ++c) {
                float wv = w1m[(size_t)c * 192 + d];
                su += gm[c] * wv;
                sv += bm[c] * wv;
            }
            u[m * 192 + d]  = su;
            vb[m * 192 + d] = sv + b1[m * 192 + d];
        }
    }
}

// ---------- fused main kernel: ZERO barriers, ZERO LDS ----------
// 512 thr = 8 fully-independent waves. Wave w owns tokens [T0+16w, +16) x ALL
// 192 dims. A-fragments gathered per-lane straight from global:
//   lane l -> token (l&15), channels (l>>4)*8 + j  (+32 per chunk).
//   Per scalar load: lanes 0..15 = 64B contiguous segment; waves w,w+1 cover
//   the two halves of each 128B line (L1/L2-friendly). A has NO reuse -> no
//   staging needed; the MFMA-layout transpose comes free from the gather.
// LN stats in-lane: lane accumulates its 192 channels; 4 lanes/token; two
// shfl_xor(16/32) give full 768-ch sums. Epilogue all-shfl. No __syncthreads.
// B-frags (L2-hot prepacked w1f) register-loaded per chunk in two 6-frag
// phases (24 VGPR). acc = 12 x f32x4 = 48 VGPR.
// No barrier can force a vmcnt drain: waves are pure independent dataflow;
// compiler emits exact counted waits. 4 waves/SIMD target (50% occupancy).
__global__ __launch_bounds__(512, 4)
void fused_main(const float* __restrict__ f0, const float* __restrict__ f1,
                const float* __restrict__ f2,
                const unsigned short* __restrict__ w1f,
                const float* __restrict__ u_g, const float* __restrict__ vb_g,
                const float* __restrict__ w2_g, const float* __restrict__ b2_g,
                float* __restrict__ out)
{
    // XCD-aware bijective swizzle: 864 = 8 * 108.
    const int bx0  = blockIdx.x;
    const int bx   = (bx0 & 7) * 108 + (bx0 >> 3);
    const int mod  = bx / TPM;
    const int tile = bx % TPM;
    const float* feat = (mod == 0) ? f0 : ((mod == 1) ? f1 : f2);
    const int T0   = tile * BT;
    const int bimg = T0 / 2304;
    const int hw0  = T0 % 2304;               // 128 | 2304: no image crossing
    const float* fbase = feat + (size_t)bimg * 768 * 2304 + hw0;

    const int tid  = threadIdx.x;
    const int l    = tid & 63;
    const int w    = tid >> 6;      // wave 0..7
    const int tok0 = w * 16;        // wave's token base within block
    const int trow = l & 15;        // lane's token within the wave
    const int kg   = l >> 4;        // lane's channel group (0..3)

    // lane's A gather base: token (tok0+trow), channel (kg*8)
    const float* aptr = fbase + (size_t)(kg * 8) * 2304 + tok0 + trow;
    const unsigned short* w1fm = w1f + (size_t)mod * 24 * 6144;

    f32x4 acc[12];
    #pragma unroll
    for (int nf = 0; nf < 12; ++nf) acc[nf] = (f32x4){0.f, 0.f, 0.f, 0.f};

    float sum = 0.f, ssq = 0.f;
    float avA[8], avB[8];           // named A double-buffer (rule #20)

#define LOADA(DST, KK)                                                         \
    _Pragma("unroll")                                                          \
    for (int j = 0; j < 8; ++j)                                                \
        DST[j] = aptr[(size_t)((KK) * 32 + j) * 2304];

#define STEPK(KK, CUR, NXT)                                                    \
    {                                                                          \
        bf16x8 af;                                                             \
        _Pragma("unroll")                                                      \
        for (int j = 0; j < 8; ++j) {                                          \
            float x = CUR[j];                                                  \
            sum += x; ssq = fmaf(x, x, ssq);                                   \
            af[j] = (short)f2bf(x);                                            \
        }                                                                      \
        if ((KK) < NCHUNK - 1) { LOADA(NXT, (KK) + 1); }                       \
        const unsigned short* bk = w1fm + (size_t)(KK) * 6144;                 \
        bf16x8 bq[6];                                                          \
        _Pragma("unroll")                                                      \
        for (int nf = 0; nf < 6; ++nf)                                         \
            bq[nf] = *reinterpret_cast<const bf16x8*>(bk + (nf * 64 + l) * 8); \
        _Pragma("unroll")                                                      \
        for (int nf = 0; nf < 6; ++nf)                                         \
            acc[nf] = __builtin_amdgcn_mfma_f32_16x16x32_bf16(                 \
                          af, bq[nf], acc[nf], 0, 0, 0);                       \
        _Pragma("unroll")                                                      \
        for (int nf = 0; nf < 6; ++nf)                                         \
            bq[nf] = *reinterpret_cast<const bf16x8*>(bk + ((nf + 6) * 64 + l) * 8); \
        _Pragma("unroll")                                                      \
        for (int nf = 0; nf < 6; ++nf)                                         \
            acc[nf + 6] = __builtin_amdgcn_mfma_f32_16x16x32_bf16(             \
                              af, bq[nf], acc[nf + 6], 0, 0, 0);               \
    }

    LOADA(avA, 0);
    STEPK(0,  avA, avB)  STEPK(1,  avB, avA)
    STEPK(2,  avA, avB)  STEPK(3,  avB, avA)
    STEPK(4,  avA, avB)  STEPK(5,  avB, avA)
    STEPK(6,  avA, avB)  STEPK(7,  avB, avA)
    STEPK(8,  avA, avB)  STEPK(9,  avB, avA)
    STEPK(10, avA, avB)  STEPK(11, avB, avA)
    STEPK(12, avA, avB)  STEPK(13, avB, avA)
    STEPK(14, avA, avB)  STEPK(15, avB, avA)
    STEPK(16, avA, avB)  STEPK(17, avB, avA)
    STEPK(18, avA, avB)  STEPK(19, avB, avA)
    STEPK(20, avA, avB)  STEPK(21, avB, avA)
    STEPK(22, avA, avB)  STEPK(23, avB, avA)
#undef STEPK
#undef LOADA

    // ---- LN stats: combine the 4 lanes per token (all in-wave) ----
    sum += __shfl_xor(sum, 16);  sum += __shfl_xor(sum, 32);
    ssq += __shfl_xor(ssq, 16);  ssq += __shfl_xor(ssq, 32);
    // now lane t (t<16 and copies) holds full sum/ssq of token t

    // ---- epilogue: affine LN fix + GELU + dot(w2) + sigmoid (all shfl) ----
    const float* um  = u_g  + mod * 192;
    const float* vbm = vb_g + mod * 192;
    const float* w2m = w2_g + mod * 192;
    const float b2v  = b2_g[mod];
    float uf[12], vbf[12], w2f[12];
    #pragma unroll
    for (int nf = 0; nf < 12; ++nf) {
        int d = nf * 16 + trow;
        uf[nf] = um[d]; vbf[nf] = vbm[d]; w2f[nf] = w2m[d];
    }
    float res[4];
    #pragma unroll
    for (int r = 0; r < 4; ++r) {
        const int tk = kg * 4 + r;           // C/D row = (l>>4)*4 + r = token
        float mu = __shfl(sum, tk) * (1.f / 768.f);
        float qq = __shfl(ssq, tk) * (1.f / 768.f);
        float rs = rsqrtf(qq - mu * mu + 1e-5f);
        float p = 0.f;
        #pragma unroll
        for (int nf = 0; nf < 12; ++nf) {
            float x = rs * (acc[nf][r] - mu * uf[nf]) + vbf[nf];
            float h = 0.5f * x * (1.f + erff(x * 0.70710678118f));  // exact GELU
            p = fmaf(h, w2f[nf], p);
        }
        p += __shfl_xor(p, 1); p += __shfl_xor(p, 2);
        p += __shfl_xor(p, 4); p += __shfl_xor(p, 8);
        res[r] = p;
    }
    if (trow == 0) {
        #pragma unroll
        for (int r = 0; r < 4; ++r)
            out[(size_t)mod * 36864 + T0 + tok0 + kg * 4 + r] =
                1.f / (1.f + expf(-(res[r] + b2v)));
    }
}

// ---------- launch ----------
extern "C" void kernel_launch(void* const* d_in, const int* in_sizes, int n_in,
                              void* d_out, int out_size, void* d_ws, size_t ws_size,
                              hipStream_t stream)
{
    const float* f0  = (const float*)d_in[0];
    const float* f1  = (const float*)d_in[1];
    const float* f2  = (const float*)d_in[2];
    const float* lng = (const float*)d_in[3];
    const float* lnb = (const float*)d_in[4];
    const float* w1  = (const float*)d_in[5];
    const float* b1  = (const float*)d_in[6];
    const float* w2  = (const float*)d_in[7];
    const float* b2  = (const float*)d_in[8];
    float* out = (float*)d_out;

    char* ws = (char*)d_ws;
    unsigned short* w1f = (unsigned short*)ws;          // 884736 B
    float* u     = (float*)(ws + 884736);               // 2304 B
    float* vb    = (float*)(ws + 887040);               // 2304 B

    prep_all  <<<dim3(75), dim3(256), 0, stream>>>(w1, lng, lnb, b1, w1f, u, vb);
    fused_main<<<dim3(3 * TPM), dim3(512), 0, stream>>>(f0, f1, f2, w1f, u, vb, w2, b2, out);
}